// Round 1
// baseline (242.354 us; speedup 1.0000x reference)
//
#include <hip/hip_runtime.h>

// Problem constants (from reference: B,S,D = 128,256,1024; BETA = 1.0)
constexpr int   Bc   = 128;
constexpr int   Sc   = 256;
constexpr int   Dc   = 1024;
constexpr float BETA = 1.0f;

constexpr int WPW   = 8;                         // s-values per wave
constexpr int SLOTS = (Sc - 2 + WPW - 1) / WPW;  // 32 wave-slots per b
constexpr int WAVES = Bc * SLOTS;                // 4096 waves
constexpr int BLOCK = 256;                       // 4 waves / block
constexpr int GRID  = WAVES * 64 / BLOCK;        // 1024 blocks

__global__ __launch_bounds__(BLOCK) void bridge_loss_kernel(
    const float* __restrict__ bridges,
    const int*   __restrict__ b_inx,
    const int*   __restrict__ neg_i,
    const int*   __restrict__ neg_j,
    float*       __restrict__ out)
{
    const int wid  = (blockIdx.x * BLOCK + threadIdx.x) >> 6;  // global wave id
    const int lane = threadIdx.x & 63;
    const int b    = wid / SLOTS;
    const int slot = wid % SLOTS;

    // Per-b time endpoints (wave-uniform)
    const float th = (float)b_inx[b * Sc];
    const float tt = (float)b_inx[b * Sc + (Sc - 1)];
    const float inv_den = 1.0f / (tt - th);

    // Cache head/tail rows in registers: lane handles d = k*256 + lane*4 .. +3
    // (each load instruction covers a contiguous 1 KiB wave segment)
    const float4* __restrict__ head4 =
        (const float4*)(bridges + (size_t)b * Sc * Dc);
    const float4* __restrict__ tail4 =
        (const float4*)(bridges + ((size_t)b * Sc + (Sc - 1)) * Dc);
    float4 h[4], t[4];
#pragma unroll
    for (int k = 0; k < 4; ++k) {
        h[k] = head4[k * 64 + lane];
        t[k] = tail4[k * 64 + lane];
    }

    float acc = 0.0f;
    const int s0 = 1 + slot * WPW;
    const int s1 = (s0 + WPW < Sc - 1) ? (s0 + WPW) : (Sc - 1);

    for (int s = s0; s < s1; ++s) {
        const float tp    = (float)b_inx[b * Sc + s];
        const float alpha = (tp - th) * inv_den;
        const float sigma = alpha * (tt - tp);
        const float inv   = 1.0f / (2.0f * sigma * sigma);

        const int j  = s - 1;
        const int ni = neg_i[b * (Sc - 2) + j];
        const int nj = neg_j[b * (Sc - 2) + j];

        const float4* __restrict__ pos4 =
            (const float4*)(bridges + ((size_t)b * Sc + s) * Dc);
        const float4* __restrict__ neg4 =
            (const float4*)(bridges + ((size_t)ni * Sc + nj) * Dc);

        float sp = 0.0f, sn = 0.0f;
#pragma unroll
        for (int k = 0; k < 4; ++k) {
            const float4 p = pos4[k * 64 + lane];
            const float4 n = neg4[k * 64 + lane];
            // mix = h + alpha*(t - h)
            const float m0 = h[k].x + alpha * (t[k].x - h[k].x);
            const float m1 = h[k].y + alpha * (t[k].y - h[k].y);
            const float m2 = h[k].z + alpha * (t[k].z - h[k].z);
            const float m3 = h[k].w + alpha * (t[k].w - h[k].w);
            const float xp0 = p.x - m0, xp1 = p.y - m1, xp2 = p.z - m2, xp3 = p.w - m3;
            const float xn0 = n.x - m0, xn1 = n.y - m1, xn2 = n.z - m2, xn3 = n.w - m3;
            sp += xp0 * xp0 + xp1 * xp1 + xp2 * xp2 + xp3 * xp3;
            sn += xn0 * xn0 + xn1 * xn1 + xn2 * xn2 + xn3 * xn3;
        }

        // Wave-wide butterfly reduction (64 lanes)
#pragma unroll
        for (int m = 32; m >= 1; m >>= 1) {
            sp += __shfl_xor(sp, m);
            sn += __shfl_xor(sn, m);
        }

        // cur = pos_dis - neg_dis + BETA = (sn - sp)*inv + BETA
        const float cur = (sn - sp) * inv + BETA;
        if (cur > 0.0f) acc += cur;
    }

    if (lane == 0 && acc != 0.0f) {
        atomicAdd(out, acc * (1.0f / (float)Bc));
    }
}

extern "C" void kernel_launch(void* const* d_in, const int* in_sizes, int n_in,
                              void* d_out, int out_size, void* d_ws, size_t ws_size,
                              hipStream_t stream) {
    const float* bridges = (const float*)d_in[0];
    const int*   b_inx   = (const int*)d_in[1];
    const int*   neg_i   = (const int*)d_in[2];
    const int*   neg_j   = (const int*)d_in[3];
    float*       out     = (float*)d_out;

    // d_out is poisoned to 0xAA before every launch — zero it.
    hipMemsetAsync(out, 0, sizeof(float), stream);

    bridge_loss_kernel<<<GRID, BLOCK, 0, stream>>>(bridges, b_inx, neg_i, neg_j, out);
}